// Round 2
// baseline (380.819 us; speedup 1.0000x reference)
//
#include <hip/hip_runtime.h>

// Emission-absorption volume renderer. fp32 in/out.
// Outputs flat: [features(3NR) | depths(NR) | opac(NR) | weights(128NR)].
//
// R5 re-decomposition: 16 lanes per ray, 8 samples per lane, 4 rays per wave.
// Rationale (rocprof): previous 64-lane/ray version was latency-bound
// (HBM 25% peak, VALU 32%, both pipes idle) — 3 KB/wave in flight and a
// 12-step serial ds_permute chain. This version: 10 KB/wave in flight
// (10x dwordx4 loads), 4-step group scan + 4-step group butterfly, and
// the per-wave fixed cost amortized over 4 rays.
//
// R6: fix compile — __builtin_nontemporal_store needs a native clang
// ext_vector_type, not HIP's float4 class. Same codegen intent
// (global_store_dwordx4 nt).
//
// NUMERICAL NOTE (carried from R3): the lane-127 sentinel delta (1e10)
// must NOT enter the prefix scan — fp32 cancellation would corrupt
// absorption_shifted near the ray end. The sentinel only feeds the final
// opacity term, where exp(-~1e10) == 0 exactly.

#define BG_OPACITY_F 1e10f

typedef float floatx4 __attribute__((ext_vector_type(4)));

__global__ __launch_bounds__(256) void ea_render_kernel(
    const float* __restrict__ dens,    // (rays, 128)
    const float* __restrict__ feats,   // (rays, 128, 3)
    const float* __restrict__ lens,    // (rays, 128)
    const float* __restrict__ dirs,    // (rays, 3)
    float* __restrict__ out_feat,      // (rays, 3)
    float* __restrict__ out_depth,     // (rays)
    float* __restrict__ out_opac,      // (rays)
    float* __restrict__ out_w,         // (rays, 128)
    int n_rays)
{
    const int lane = threadIdx.x & 63;
    const int wave = threadIdx.x >> 6;               // 0..3
    const int g    = lane >> 4;                      // ray-group within wave
    const int t    = lane & 15;                      // sub-lane within group
    const long ray = (long)blockIdx.x * 16 + wave * 4 + g;
    if (ray >= n_rays) return;

    const long base = ray * 128;
    const int  n0   = t * 8;                         // first sample owned

    // ---- bulk loads: 160 B/lane, all independent dwordx4 ----
    const float4 dA = *(const float4*)(dens + base + n0);
    const float4 dB = *(const float4*)(dens + base + n0 + 4);
    const float4 lA = *(const float4*)(lens + base + n0);
    const float4 lB = *(const float4*)(lens + base + n0 + 4);

    const float* fp = feats + base * 3 + (long)n0 * 3;   // 96 B, 16B-aligned
    const float4 f0 = *(const float4*)(fp +  0);
    const float4 f1 = *(const float4*)(fp +  4);
    const float4 f2 = *(const float4*)(fp +  8);
    const float4 f3 = *(const float4*)(fp + 12);
    const float4 f4 = *(const float4*)(fp + 16);
    const float4 f5 = *(const float4*)(fp + 20);

    // ray direction norm (12 B, uniform within the 16-lane group -> L1 hit)
    const float* dp = dirs + ray * 3;
    const float dx = dp[0], dy = dp[1], dz = dp[2];
    const float dn = sqrtf(dx * dx + dy * dy + dz * dz);

    const float l[8]  = {lA.x, lA.y, lA.z, lA.w, lB.x, lB.y, lB.z, lB.w};
    const float dv[8] = {dA.x, dA.y, dA.z, dA.w, dB.x, dB.y, dB.z, dB.w};

    // l[0] of sub-lane t+1 (needed for delta of our last sample).
    // At t==15 the shuffle crosses into the next ray's group — unused there,
    // since n==127 takes the sentinel delta instead.
    const float lnext = __shfl_down(lA.x, 1, 64);

    // ---- weighted = delta * dir_norm * relu(dens) ----
    float w[8];
    #pragma unroll
    for (int i = 0; i < 7; ++i)
        w[i] = (l[i + 1] - l[i]) * dn * fmaxf(dv[i], 0.0f);
    const float delta7 = (t == 15) ? BG_OPACITY_F : (lnext - l[7]);
    w[7] = delta7 * dn * fmaxf(dv[7], 0.0f);
    const float w7s = (t == 15) ? 0.0f : w[7];       // sentinel excluded

    // lane-local sum of real terms
    const float s = w[0] + w[1] + w[2] + w[3] + w[4] + w[5] + w[6] + w7s;

    // ---- 16-lane inclusive scan of per-lane sums (4 dependent steps) ----
    float inc = s;
    #pragma unroll
    for (int off = 1; off < 16; off <<= 1) {
        const float u = __shfl_up(inc, off, 64);
        if (t >= off) inc += u;                      // t-mask keeps groups separate
    }
    const float excl = inc - s;                      // sum over all n < n0

    // ---- weights: wgt[i] = (1 - exp(-w[i])) * exp(-prefix_excl[i]) ----
    float a = __expf(-excl);                         // absorption_shifted at n0
    float wgt[8];
    #pragma unroll
    for (int i = 0; i < 8; ++i) {
        const float ei = __expf(-w[i]);              // t==15,i==7: exp(-~1e10)=0
        wgt[i] = (1.0f - ei) * a;
        a *= ei;
    }

    // ---- per-lane partials for depth + 3 feature channels ----
    const float f[24] = {f0.x, f0.y, f0.z, f0.w, f1.x, f1.y, f1.z, f1.w,
                         f2.x, f2.y, f2.z, f2.w, f3.x, f3.y, f3.z, f3.w,
                         f4.x, f4.y, f4.z, f4.w, f5.x, f5.y, f5.z, f5.w};
    float pd = 0.0f, fr = 0.0f, fg = 0.0f, fb = 0.0f;
    #pragma unroll
    for (int i = 0; i < 8; ++i) {
        pd += wgt[i] * l[i];
        fr += wgt[i] * f[3 * i + 0];
        fg += wgt[i] * f[3 * i + 1];
        fb += wgt[i] * f[3 * i + 2];
    }

    // ---- 16-lane butterfly reductions (4 steps, xor stays within group) ----
    #pragma unroll
    for (int off = 8; off; off >>= 1) {
        pd += __shfl_xor(pd, off, 64);
        fr += __shfl_xor(fr, off, 64);
        fg += __shfl_xor(fg, off, 64);
        fb += __shfl_xor(fb, off, 64);
    }

    // ---- stores ----
    // weights: streamed, never re-read by us -> nontemporal to protect L2/L3
    // residency of the 337 MB input set.
    const floatx4 wv0 = {wgt[0], wgt[1], wgt[2], wgt[3]};
    const floatx4 wv1 = {wgt[4], wgt[5], wgt[6], wgt[7]};
    __builtin_nontemporal_store(wv0, (floatx4*)(out_w + base + n0));
    __builtin_nontemporal_store(wv1, (floatx4*)(out_w + base + n0 + 4));

    if (t == 15) {
        // inc == total real weighted sum for this ray; re-add sentinel term.
        out_opac[ray] = 1.0f - __expf(-(inc + w[7]));
    }
    if (t == 0) {
        // features += (1 - opac) * BG_COLOR with BG_COLOR == 0 -> no-op
        out_feat[ray * 3 + 0] = fr;
        out_feat[ray * 3 + 1] = fg;
        out_feat[ray * 3 + 2] = fb;
        out_depth[ray] = pd;
    }
}

extern "C" void kernel_launch(void* const* d_in, const int* in_sizes, int n_in,
                              void* d_out, int out_size, void* d_ws, size_t ws_size,
                              hipStream_t stream) {
    // Input order verified (R4 decode): dens(0), feats(1), lens(2), dirs(3).
    const float* dens  = (const float*)d_in[0];  // (B,R,N,1)
    const float* feats = (const float*)d_in[1];  // (B,R,N,3)
    const float* lens  = (const float*)d_in[2];  // (B,R,N)
    const float* dirs  = (const float*)d_in[3];  // (B,R,3)

    const int n_rays = in_sizes[3] / 3;          // B*R = 131072

    float* out = (float*)d_out;
    float* out_feat  = out;                       // (rays, 3)
    float* out_depth = out + (long)n_rays * 3;    // (rays, 1)
    float* out_opac  = out + (long)n_rays * 4;    // (rays, 1)
    float* out_w     = out + (long)n_rays * 5;    // (rays, 128)

    const int blocks = (n_rays + 15) / 16;        // 16 rays (4 waves x 4) / block
    ea_render_kernel<<<blocks, 256, 0, stream>>>(
        dens, feats, lens, dirs, out_feat, out_depth, out_opac, out_w, n_rays);
}